// Round 1
// baseline (541.460 us; speedup 1.0000x reference)
//
#include <hip/hip_runtime.h>
#include <math.h>

#define B_    64
#define T_    2048
#define DRNN  1024
#define DEMB  512
#define DATT  128
#define NF    32
#define KS    31
#define PADL  15
#define MP    64   // padded row pitch for merged conv matrix M
#define TT    32   // t's per thread-tile in energy phase
#define CT    64   // t's per block (chunk)
#define NC    (T_/CT)   // 32 chunks per batch row

__device__ __forceinline__ float fast_tanh(float x){
    float e2 = __expf(2.0f * x);
    return 1.0f - 2.0f / (e2 + 1.0f);
}

// ---------------------------------------------------------------------------
// K1: pq[b,a] = hidden[b,:] . Wq[a,:]   (blocks 0..63, split-K over 2 thread
//     groups to halve the per-thread load chain)
//     M[a, c*31+k] = sum_f Wd[a,f]*conv_w[f,c,k]   (block 64)
// ---------------------------------------------------------------------------
__global__ __launch_bounds__(256) void prep_kernel(
    const float* __restrict__ hidden, const float* __restrict__ Wq,
    const float* __restrict__ Wd, const float* __restrict__ convw,
    float* __restrict__ pq, float* __restrict__ M)
{
    const int blk = blockIdx.x;
    const int tid = threadIdx.x;
    if (blk < B_) {
        __shared__ float sh[DRNN];
        __shared__ float part[DATT];
        const int b = blk;
        #pragma unroll
        for (int i = 0; i < DRNN/256; ++i) sh[tid + 256*i] = hidden[b*DRNN + tid + 256*i];
        __syncthreads();
        const int a = tid & 127;
        const int h = tid >> 7;              // k-half
        const float4* wq4 = (const float4*)(Wq + a*DRNN + h*(DRNN/2));
        const float*  shh = sh + h*(DRNN/2);
        float acc = 0.f;
        #pragma unroll 8
        for (int k = 0; k < DRNN/8; ++k){
            float4 w = wq4[k];
            acc = fmaf(w.x, shh[4*k+0], acc);
            acc = fmaf(w.y, shh[4*k+1], acc);
            acc = fmaf(w.z, shh[4*k+2], acc);
            acc = fmaf(w.w, shh[4*k+3], acc);
        }
        if (h) part[a] = acc;
        __syncthreads();
        if (!h) pq[b*DATT + a] = acc + part[a];
    } else {
        const int a = tid & 127;
        const int h = tid >> 7;              // each half does 31 of the 62 cols
        float wd[NF];
        #pragma unroll
        for (int f = 0; f < NF; ++f) wd[f] = Wd[a*NF + f];
        for (int ck = h*KS; ck < h*KS + KS; ++ck){
            float acc = 0.f;
            #pragma unroll
            for (int f = 0; f < NF; ++f) acc = fmaf(wd[f], convw[f*2*KS + ck], acc);
            M[a*MP + ck] = acc;
        }
    }
}

// ---------------------------------------------------------------------------
// K2 (energy + chunk softmax partials) — compute-bound, high-VGPR kernel.
// Grid: x = NC, y = B. Block = 256 (128 a x 2 t-tiles of TT=32).
//  - pm prefetched into registers BEFORE the FIR (latency hidden under
//    ~2000 FMA), with a wave-uniform mask skip (masked energies are
//    discarded by the softmax, so their pm rows need not be read).
//  - writes p_t (unscaled), per-chunk max m_c and sum s_c.
// ---------------------------------------------------------------------------
__global__ __launch_bounds__(256) void energy_kernel(
    const float* __restrict__ pm, const float* __restrict__ awcat,
    const float* __restrict__ pq, const float* __restrict__ M,
    const float* __restrict__ Wv, const int* __restrict__ mask,
    float* __restrict__ pbuf, float* __restrict__ pmax,
    float* __restrict__ psum)
{
    const int b   = blockIdx.y;
    const int cx  = blockIdx.x;
    const int t0  = cx * CT;
    const int tid = threadIdx.x;
    const int s   = tid >> 7;            // t-tile 0/1
    const int a   = tid & 127;
    const int ts  = t0 + TT * s;

    __shared__ float saw0[96], saw1[96];     // aw[c, t0-15 .. t0+78]
    __shared__ float sred[2][2][TT];         // [tile][a-half][t]

    for (int i = tid; i < 94; i += 256){
        int tt = t0 - PADL + i;
        bool ok = (tt >= 0) && (tt < T_);
        saw0[i] = ok ? awcat[(b*2+0)*T_ + tt] : 0.f;
        saw1[i] = ok ? awcat[(b*2+1)*T_ + tt] : 0.f;
    }
    __syncthreads();

    // ---- prefetch pm (wave-uniform mask skip; masked rows never read) ----
    const float* pmb  = pm + ((size_t)(b*T_ + ts)) * DATT + a;
    const int*   mrow = mask + b*T_ + ts;
    float pmv[TT];
    #pragma unroll
    for (int t = 0; t < TT; ++t){
        int mk = __builtin_amdgcn_readfirstlane(mrow[t]);   // uniform across wave
        pmv[t] = mk ? 0.f : pmb[(size_t)t * DATT];
    }

    // ---- register FIR over merged conv matrix ----
    float Ma0[KS], Ma1[KS];
    const float* Mrow = M + a*MP;
    #pragma unroll
    for (int k = 0; k < KS; ++k){ Ma0[k] = Mrow[k]; Ma1[k] = Mrow[KS + k]; }
    const float pqa = pq[b*DATT + a];
    const float wv  = Wv[a];

    float acc[TT];
    #pragma unroll
    for (int t = 0; t < TT; ++t) acc[t] = pqa;

    #pragma unroll
    for (int j = 0; j < TT + KS - 1; ++j){
        const float av0 = saw0[j + TT*s];
        const float av1 = saw1[j + TT*s];
        const int tlo = (j - KS + 1) > 0 ? (j - KS + 1) : 0;
        const int thi = (j < TT - 1) ? j : (TT - 1);
        #pragma unroll
        for (int t = tlo; t <= thi; ++t){
            acc[t] = fmaf(Ma0[j - t], av0, acc[t]);
            acc[t] = fmaf(Ma1[j - t], av1, acc[t]);
        }
    }

    // tanh + v-projection (masked t's produce bounded garbage, discarded below)
    #pragma unroll
    for (int t = 0; t < TT; ++t){
        acc[t] = wv * fast_tanh(acc[t] + pmv[t]);
    }

    const int lane = tid & 63;
    const int half = a >> 6;
    #pragma unroll
    for (int t = 0; t < TT; ++t){
        float r = acc[t];
        r += __shfl_xor(r, 1, 64);  r += __shfl_xor(r, 2, 64);
        r += __shfl_xor(r, 4, 64);  r += __shfl_xor(r, 8, 64);
        r += __shfl_xor(r, 16, 64); r += __shfl_xor(r, 32, 64);
        if (lane == 0) sred[s][half][t] = r;
    }
    __syncthreads();

    // ---- chunk softmax partials (single wave, 64 t's) ----
    if (tid < 64){
        const int t = t0 + tid;
        float e = sred[tid>>5][0][tid&31] + sred[tid>>5][1][tid&31];
        const int mk = mask[b*T_ + t];
        float mval = mk ? -1e30f : e;
        #pragma unroll
        for (int off = 1; off < 64; off <<= 1) mval = fmaxf(mval, __shfl_xor(mval, off, 64));
        const float pval = mk ? 0.f : __expf(e - mval);
        float sv = pval;
        #pragma unroll
        for (int off = 1; off < 64; off <<= 1) sv += __shfl_xor(sv, off, 64);
        pbuf[b*T_ + t] = pval;
        if (tid == 0){
            pmax[b*NC + cx] = mval;
            psum[b*NC + cx] = sv;
        }
    }
}

// ---------------------------------------------------------------------------
// K3 (context) — pure streaming kernel, ~30 VGPRs -> max occupancy.
// Each block redundantly reduces the 32 chunk partials of its b (64 floats,
// L2-hit) to get the global scale, applies it, writes wout and the
// PRE-SCALED partial context. Masked rows (w==0) skipped wave-uniformly.
// ---------------------------------------------------------------------------
__global__ __launch_bounds__(256) void ctx_kernel(
    const float* __restrict__ pbuf, const float* __restrict__ pmax,
    const float* __restrict__ psum, const float* __restrict__ memory,
    float* __restrict__ pctx, float* __restrict__ wout)
{
    const int b   = blockIdx.y;
    const int cx  = blockIdx.x;
    const int t0  = cx * CT;
    const int tid = threadIdx.x;

    __shared__ float sw[CT];
    __shared__ float4 sacc[128];
    __shared__ float s_scale;

    if (tid < 64){
        float mv = (tid < NC) ? pmax[b*NC + tid] : -1e30f;
        float sv = (tid < NC) ? psum[b*NC + tid] : 0.f;
        float g = mv;
        #pragma unroll
        for (int off = 1; off < 64; off <<= 1) g = fmaxf(g, __shfl_xor(g, off, 64));
        float z = sv * __expf(mv - g);
        #pragma unroll
        for (int off = 1; off < 64; off <<= 1) z += __shfl_xor(z, off, 64);
        if (tid == cx) s_scale = __expf(mv - g) / z;   // this chunk's scale
    }
    __syncthreads();
    const float sc = s_scale;

    if (tid < CT){
        const float w = pbuf[b*T_ + t0 + tid] * sc;
        sw[tid] = w;
        wout[b*T_ + t0 + tid] = w;   // final attention weight
    }
    __syncthreads();

    const int col = tid & 127;   // float4 column (DEMB/4 = 128)
    const int row = tid >> 7;    // 2 t's in flight
    float4 a4 = make_float4(0.f, 0.f, 0.f, 0.f);
    const float4* mem4 = (const float4*)memory + ((size_t)(b*T_ + t0))*(DEMB/4) + col;
    for (int tt = row; tt < CT; tt += 2){
        const float w = sw[tt];          // wave-uniform (LDS broadcast)
        if (w != 0.f){
            const float4 m = mem4[(size_t)tt * (DEMB/4)];
            a4.x = fmaf(w, m.x, a4.x);
            a4.y = fmaf(w, m.y, a4.y);
            a4.z = fmaf(w, m.z, a4.z);
            a4.w = fmaf(w, m.w, a4.w);
        }
    }
    if (row == 1) sacc[col] = a4;
    __syncthreads();
    if (row == 0){
        const float4 o = sacc[col];
        float4* dst = (float4*)(pctx + ((size_t)(b*NC + cx))*DEMB) + col;
        *dst = make_float4(a4.x + o.x, a4.y + o.y, a4.z + o.z, a4.w + o.w);
    }
}

// ---------------------------------------------------------------------------
// K4 (finalize): ctx[b,d] = sum_c pctx_c[d]  (partials already scaled)
// ---------------------------------------------------------------------------
__global__ __launch_bounds__(256) void finalize_kernel(
    const float* __restrict__ pctx, float* __restrict__ ctx)
{
    const int b = blockIdx.x;
    const int tid = threadIdx.x;
    float2 a2 = make_float2(0.f, 0.f);
    const float2* pc2 = (const float2*)(pctx + (size_t)b*NC*DEMB) + tid;
    #pragma unroll
    for (int c = 0; c < NC; ++c){
        const float2 v = pc2[(size_t)c * (DEMB/2)];
        a2.x += v.x;
        a2.y += v.y;
    }
    ((float2*)(ctx + b*DEMB))[tid] = a2;
}

// ---------------------------------------------------------------------------
extern "C" void kernel_launch(void* const* d_in, const int* in_sizes, int n_in,
                              void* d_out, int out_size, void* d_ws, size_t ws_size,
                              hipStream_t stream)
{
    const float* hidden = (const float*)d_in[0];   // (B, D_RNN)
    const float* memory = (const float*)d_in[1];   // (B, T, D_EMB)
    const float* pm     = (const float*)d_in[2];   // (B, T, D_ATT)
    const float* awcat  = (const float*)d_in[3];   // (B, 2, T)
    const int*   mask   = (const int*)d_in[4];     // (B, T)
    const float* Wq     = (const float*)d_in[5];   // (D_ATT, D_RNN)
    const float* Wv     = (const float*)d_in[6];   // (1, D_ATT)
    const float* convw  = (const float*)d_in[7];   // (NF, 2, KS)
    const float* Wd     = (const float*)d_in[8];   // (D_ATT, NF)

    float* out  = (float*)d_out;
    float* ctx  = out;               // (B, D_EMB)
    float* wout = out + B_*DEMB;     // (B, T)

    float* pq    = (float*)d_ws;             // 8192
    float* M     = pq   + B_*DATT;           // 8192
    float* pbuf  = M    + DATT*MP;           // B*T = 131072
    float* pmax  = pbuf + B_*T_;             // B*NC = 2048
    float* psum  = pmax + B_*NC;             // 2048
    float* pctx  = psum + B_*NC;             // B*NC*DEMB = 4 MB

    prep_kernel<<<dim3(B_ + 1), 256, 0, stream>>>(hidden, Wq, Wd, convw, pq, M);
    energy_kernel<<<dim3(NC, B_), 256, 0, stream>>>(pm, awcat, pq, M, Wv, mask,
                                                    pbuf, pmax, psum);
    ctx_kernel<<<dim3(NC, B_), 256, 0, stream>>>(pbuf, pmax, psum, memory,
                                                 pctx, wout);
    finalize_kernel<<<dim3(B_), 256, 0, stream>>>(pctx, ctx);
}

// Round 2
// 456.770 us; speedup vs baseline: 1.1854x; 1.1854x over previous
//
#include <hip/hip_runtime.h>
#include <math.h>

#define B_    64
#define T_    2048
#define DRNN  1024
#define DEMB  512
#define DATT  128
#define NF    32
#define KS    31
#define PADL  15
#define MP    64   // padded row pitch for merged conv matrix M
#define TT    32   // t's per thread-tile in energy phase
#define CT    64   // t's per block (chunk)
#define NC    (T_/CT)   // 32 chunks per batch row

__device__ __forceinline__ float fast_tanh(float x){
    float e2 = __expf(2.0f * x);
    return 1.0f - 2.0f / (e2 + 1.0f);
}

// ---------------------------------------------------------------------------
// K1: pq[b,a] = hidden[b,:] . Wq[a,:]   (blocks 0..63)
//     M[a, c*31+k] = sum_f Wd[a,f]*conv_w[f,c,k]   (block 64)
// ---------------------------------------------------------------------------
__global__ __launch_bounds__(128) void prep_kernel(
    const float* __restrict__ hidden, const float* __restrict__ Wq,
    const float* __restrict__ Wd, const float* __restrict__ convw,
    float* __restrict__ pq, float* __restrict__ M)
{
    const int blk = blockIdx.x;
    const int a = threadIdx.x;   // 128 threads
    if (blk < B_) {
        __shared__ float sh[DRNN];
        const int b = blk;
        #pragma unroll
        for (int i = 0; i < DRNN/128; ++i) sh[a + 128*i] = hidden[b*DRNN + a + 128*i];
        __syncthreads();
        const float4* wq4 = (const float4*)(Wq + a*DRNN);
        float acc = 0.f;
        #pragma unroll 4
        for (int k = 0; k < DRNN/4; ++k){
            float4 w = wq4[k];
            acc = fmaf(w.x, sh[4*k+0], acc);
            acc = fmaf(w.y, sh[4*k+1], acc);
            acc = fmaf(w.z, sh[4*k+2], acc);
            acc = fmaf(w.w, sh[4*k+3], acc);
        }
        pq[b*DATT + a] = acc;
    } else {
        float wd[NF];
        #pragma unroll
        for (int f = 0; f < NF; ++f) wd[f] = Wd[a*NF + f];
        for (int ck = 0; ck < 2*KS; ++ck){
            float acc = 0.f;
            #pragma unroll
            for (int f = 0; f < NF; ++f) acc = fmaf(wd[f], convw[f*2*KS + ck], acc);
            M[a*MP + ck] = acc;
        }
    }
}

// ---------------------------------------------------------------------------
// K2 (fused energy + chunk-softmax + partial context), flash-attention style.
// Grid: x = NC (=32 chunks of 64 t), y = B. Block = 256.
// Phase 1: lane=a energy (register FIR over merged conv matrix M).
// Phase 2: chunk-local softmax partials m_c, s_c, p_t = exp(e_t - m_c),
//          then BALLOT-COMPACT the nonzero (p, t) pairs into LDS so phase 3
//          has no data-dependent branch.
// Phase 3: pctx_c[d] = sum over compacted rows of p_t * mem[t,d].
//          Branch-free, manually unrolled x4 -> 4 global loads in flight
//          per thread (the round-0 per-row `if (w!=0)` broke load batching
//          and left the dominant 128 MB stream latency-bound).
// ---------------------------------------------------------------------------
__global__ __launch_bounds__(256) void fused_kernel(
    const float* __restrict__ pm, const float* __restrict__ awcat,
    const float* __restrict__ pq, const float* __restrict__ M,
    const float* __restrict__ Wv, const int* __restrict__ mask,
    const float* __restrict__ memory,
    float* __restrict__ pbuf, float* __restrict__ pmax,
    float* __restrict__ psum, float* __restrict__ pctx)
{
    const int b   = blockIdx.y;
    const int cx  = blockIdx.x;
    const int t0  = cx * CT;             // block covers [t0, t0+64)
    const int tid = threadIdx.x;
    const int s   = tid >> 7;            // tile 0/1
    const int a   = tid & 127;
    const int ts  = t0 + TT * s;

    __shared__ float saw0[96], saw1[96];     // aw[c, t0-15 .. t0+78]
    __shared__ float sred[2][2][TT];         // [tile][a-half][t]
    __shared__ float2 swt[CT];               // compacted (p, t-as-bits)
    __shared__ int   scount;                 // number of compacted rows
    __shared__ float4 sacc[128];

    for (int i = tid; i < 94; i += 256){
        int tt = t0 - PADL + i;
        bool ok = (tt >= 0) && (tt < T_);
        saw0[i] = ok ? awcat[(b*2+0)*T_ + tt] : 0.f;
        saw1[i] = ok ? awcat[(b*2+1)*T_ + tt] : 0.f;
    }
    __syncthreads();

    // ---- Phase 1: energies ----
    float Ma0[KS], Ma1[KS];
    const float* Mrow = M + a*MP;
    #pragma unroll
    for (int k = 0; k < KS; ++k){ Ma0[k] = Mrow[k]; Ma1[k] = Mrow[KS + k]; }
    const float pqa = pq[b*DATT + a];
    const float wv  = Wv[a];

    float acc[TT];
    #pragma unroll
    for (int t = 0; t < TT; ++t) acc[t] = pqa;

    #pragma unroll
    for (int j = 0; j < TT + KS - 1; ++j){
        const float av0 = saw0[j + TT*s];
        const float av1 = saw1[j + TT*s];
        const int tlo = (j - KS + 1) > 0 ? (j - KS + 1) : 0;
        const int thi = (j < TT - 1) ? j : (TT - 1);
        #pragma unroll
        for (int t = tlo; t <= thi; ++t){
            acc[t] = fmaf(Ma0[j - t], av0, acc[t]);
            acc[t] = fmaf(Ma1[j - t], av1, acc[t]);
        }
    }

    const float* pmb = pm + ((size_t)(b*T_ + ts)) * DATT + a;
    #pragma unroll
    for (int t = 0; t < TT; ++t){
        float x = acc[t] + pmb[(size_t)t * DATT];
        acc[t] = wv * fast_tanh(x);
    }

    const int lane = tid & 63;
    const int half = a >> 6;
    #pragma unroll
    for (int t = 0; t < TT; ++t){
        float r = acc[t];
        r += __shfl_xor(r, 1, 64);  r += __shfl_xor(r, 2, 64);
        r += __shfl_xor(r, 4, 64);  r += __shfl_xor(r, 8, 64);
        r += __shfl_xor(r, 16, 64); r += __shfl_xor(r, 32, 64);
        if (lane == 0) sred[s][half][t] = r;
    }
    __syncthreads();

    // ---- Phase 2: chunk softmax partials + ballot-compaction (1 wave) ----
    if (tid < 64){
        const int t = t0 + tid;
        float e = sred[tid>>5][0][tid&31] + sred[tid>>5][1][tid&31];
        const int mk = mask[b*T_ + t];
        float mval = mk ? -1e30f : e;
        #pragma unroll
        for (int off = 1; off < 64; off <<= 1) mval = fmaxf(mval, __shfl_xor(mval, off, 64));
        const float pval = mk ? 0.f : __expf(e - mval);
        float sv = pval;
        #pragma unroll
        for (int off = 1; off < 64; off <<= 1) sv += __shfl_xor(sv, off, 64);
        pbuf[b*T_ + t] = pval;
        const unsigned long long bal = __ballot(pval != 0.f);
        if (pval != 0.f){
            const int pfx = (int)__popcll(bal & ((1ull << tid) - 1ull));
            swt[pfx] = make_float2(pval, __int_as_float(tid));
        }
        if (tid == 0){
            scount = (int)__popcll(bal);
            pmax[b*NC + cx] = mval;
            psum[b*NC + cx] = sv;
        }
    }
    __syncthreads();

    // ---- Phase 3: partial context over compacted rows, branch-free ----
    const int n   = scount;
    const int col = tid & 127;   // float4 column (DEMB/4 = 128)
    const int row = tid >> 7;    // 2 entries in flight
    float4 a4 = make_float4(0.f, 0.f, 0.f, 0.f);
    const float4* mem4 = (const float4*)memory + ((size_t)(b*T_ + t0))*(DEMB/4) + col;

    int i = row;
    for (; i + 6 < n; i += 8){
        const float2 e0 = swt[i];
        const float2 e1 = swt[i+2];
        const float2 e2 = swt[i+4];
        const float2 e3 = swt[i+6];
        const float4 m0 = mem4[(size_t)__float_as_int(e0.y) * (DEMB/4)];
        const float4 m1 = mem4[(size_t)__float_as_int(e1.y) * (DEMB/4)];
        const float4 m2 = mem4[(size_t)__float_as_int(e2.y) * (DEMB/4)];
        const float4 m3 = mem4[(size_t)__float_as_int(e3.y) * (DEMB/4)];
        a4.x = fmaf(e0.x, m0.x, a4.x); a4.y = fmaf(e0.x, m0.y, a4.y);
        a4.z = fmaf(e0.x, m0.z, a4.z); a4.w = fmaf(e0.x, m0.w, a4.w);
        a4.x = fmaf(e1.x, m1.x, a4.x); a4.y = fmaf(e1.x, m1.y, a4.y);
        a4.z = fmaf(e1.x, m1.z, a4.z); a4.w = fmaf(e1.x, m1.w, a4.w);
        a4.x = fmaf(e2.x, m2.x, a4.x); a4.y = fmaf(e2.x, m2.y, a4.y);
        a4.z = fmaf(e2.x, m2.z, a4.z); a4.w = fmaf(e2.x, m2.w, a4.w);
        a4.x = fmaf(e3.x, m3.x, a4.x); a4.y = fmaf(e3.x, m3.y, a4.y);
        a4.z = fmaf(e3.x, m3.z, a4.z); a4.w = fmaf(e3.x, m3.w, a4.w);
    }
    for (; i < n; i += 2){
        const float2 e = swt[i];
        const float4 m = mem4[(size_t)__float_as_int(e.y) * (DEMB/4)];
        a4.x = fmaf(e.x, m.x, a4.x); a4.y = fmaf(e.x, m.y, a4.y);
        a4.z = fmaf(e.x, m.z, a4.z); a4.w = fmaf(e.x, m.w, a4.w);
    }

    if (row == 1) sacc[col] = a4;
    __syncthreads();
    if (row == 0){
        const float4 o = sacc[col];
        float4* dst = (float4*)(pctx + ((size_t)(b*NC + cx))*DEMB) + col;
        *dst = make_float4(a4.x + o.x, a4.y + o.y, a4.z + o.z, a4.w + o.w);
    }
}

// ---------------------------------------------------------------------------
// K3 (finalize): per b — global max/Z from chunk partials, then
//   ctx[d]  = sum_c scale_c * pctx_c[d],  scale_c = exp(m_c - g)/Z
//   w[t]    = p[t] * scale_{c(t)}
// ---------------------------------------------------------------------------
__global__ __launch_bounds__(256) void finalize_kernel(
    const float* __restrict__ pbuf, const float* __restrict__ pmax,
    const float* __restrict__ psum, const float* __restrict__ pctx,
    float* __restrict__ ctx, float* __restrict__ wout)
{
    const int b = blockIdx.x;
    const int tid = threadIdx.x;
    __shared__ float sscale[NC];

    if (tid < 64){
        float mv = (tid < NC) ? pmax[b*NC + tid] : -1e30f;
        float sv = (tid < NC) ? psum[b*NC + tid] : 0.f;
        float g = mv;
        #pragma unroll
        for (int off = 1; off < 64; off <<= 1) g = fmaxf(g, __shfl_xor(g, off, 64));
        float z = sv * __expf(mv - g);
        #pragma unroll
        for (int off = 1; off < 64; off <<= 1) z += __shfl_xor(z, off, 64);
        if (tid < NC) sscale[tid] = __expf(mv - g) / z;
    }
    __syncthreads();

    // ctx: 256 threads x float2 = 512 d's
    float2 a2 = make_float2(0.f, 0.f);
    const float2* pc2 = (const float2*)(pctx + (size_t)b*NC*DEMB) + tid;
    #pragma unroll
    for (int c = 0; c < NC; ++c){
        const float sc = sscale[c];
        if (sc != 0.f){
            const float2 v = pc2[(size_t)c * (DEMB/2)];
            a2.x = fmaf(sc, v.x, a2.x);
            a2.y = fmaf(sc, v.y, a2.y);
        }
    }
    ((float2*)(ctx + b*DEMB))[tid] = a2;

    // weights
    #pragma unroll
    for (int i = 0; i < T_/256; ++i){
        const int t = tid + 256*i;
        wout[b*T_ + t] = pbuf[b*T_ + t] * sscale[t >> 6];
    }
}

// ---------------------------------------------------------------------------
extern "C" void kernel_launch(void* const* d_in, const int* in_sizes, int n_in,
                              void* d_out, int out_size, void* d_ws, size_t ws_size,
                              hipStream_t stream)
{
    const float* hidden = (const float*)d_in[0];   // (B, D_RNN)
    const float* memory = (const float*)d_in[1];   // (B, T, D_EMB)
    const float* pm     = (const float*)d_in[2];   // (B, T, D_ATT)
    const float* awcat  = (const float*)d_in[3];   // (B, 2, T)
    const int*   mask   = (const int*)d_in[4];     // (B, T)
    const float* Wq     = (const float*)d_in[5];   // (D_ATT, D_RNN)
    const float* Wv     = (const float*)d_in[6];   // (1, D_ATT)
    const float* convw  = (const float*)d_in[7];   // (NF, 2, KS)
    const float* Wd     = (const float*)d_in[8];   // (D_ATT, NF)

    float* out  = (float*)d_out;
    float* ctx  = out;               // (B, D_EMB)
    float* wout = out + B_*DEMB;     // (B, T)

    float* pq    = (float*)d_ws;             // 8192
    float* M     = pq   + B_*DATT;           // 8192
    float* pbuf  = M    + DATT*MP;           // B*T = 131072
    float* pmax  = pbuf + B_*T_;             // B*NC = 2048
    float* psum  = pmax + B_*NC;             // 2048
    float* pctx  = psum + B_*NC;             // B*NC*DEMB = 4 MB

    prep_kernel<<<dim3(B_ + 1), 128, 0, stream>>>(hidden, Wq, Wd, convw, pq, M);
    fused_kernel<<<dim3(NC, B_), 256, 0, stream>>>(pm, awcat, pq, M, Wv, mask,
                                                   memory, pbuf, pmax, psum, pctx);
    finalize_kernel<<<dim3(B_), 256, 0, stream>>>(pbuf, pmax, psum, pctx, ctx, wout);
}

// Round 3
// 441.238 us; speedup vs baseline: 1.2271x; 1.0352x over previous
//
#include <hip/hip_runtime.h>
#include <math.h>

#define B_    64
#define T_    2048
#define DRNN  1024
#define DEMB  512
#define DATT  128
#define NF    32
#define KS    31
#define PADL  15
#define MP    64   // padded row pitch for merged conv matrix M
#define TT    32   // t's per thread-tile in energy phase
#define CT    64   // t's per block (chunk)
#define NC    (T_/CT)   // 32 chunks per batch row

__device__ __forceinline__ float fast_tanh(float x){
    float e2 = __expf(2.0f * x);
    return 1.0f - 2.0f / (e2 + 1.0f);
}

// ---------------------------------------------------------------------------
// K1: pq[b,a] = hidden[b,:] . Wq[a,:]   (blocks 0..63)
//     M[a, c*31+k] = sum_f Wd[a,f]*conv_w[f,c,k]   (block 64)
// ---------------------------------------------------------------------------
__global__ __launch_bounds__(128) void prep_kernel(
    const float* __restrict__ hidden, const float* __restrict__ Wq,
    const float* __restrict__ Wd, const float* __restrict__ convw,
    float* __restrict__ pq, float* __restrict__ M)
{
    const int blk = blockIdx.x;
    const int a = threadIdx.x;   // 128 threads
    if (blk < B_) {
        __shared__ float sh[DRNN];
        const int b = blk;
        #pragma unroll
        for (int i = 0; i < DRNN/128; ++i) sh[a + 128*i] = hidden[b*DRNN + a + 128*i];
        __syncthreads();
        const float4* wq4 = (const float4*)(Wq + a*DRNN);
        float acc = 0.f;
        #pragma unroll 4
        for (int k = 0; k < DRNN/4; ++k){
            float4 w = wq4[k];
            acc = fmaf(w.x, sh[4*k+0], acc);
            acc = fmaf(w.y, sh[4*k+1], acc);
            acc = fmaf(w.z, sh[4*k+2], acc);
            acc = fmaf(w.w, sh[4*k+3], acc);
        }
        pq[b*DATT + a] = acc;
    } else {
        float wd[NF];
        #pragma unroll
        for (int f = 0; f < NF; ++f) wd[f] = Wd[a*NF + f];
        for (int ck = 0; ck < 2*KS; ++ck){
            float acc = 0.f;
            #pragma unroll
            for (int f = 0; f < NF; ++f) acc = fmaf(wd[f], convw[f*2*KS + ck], acc);
            M[a*MP + ck] = acc;
        }
    }
}

// ---------------------------------------------------------------------------
// K2 (fused energy + chunk-softmax + partial context), flash-attention style.
// Grid: x = NC (=32 chunks of 64 t), y = B. Block = 256.
// Phase 1: acc[t] init = pq + pm[t]  (pm loads issued FIRST -> the whole FIR
//          is the latency-hiding window; zero extra VGPRs since acc is the
//          load destination), then register FIR over merged conv matrix M,
//          then tanh (no loads left on the tail), then a multi-value
//          butterfly reduction: 32 shuffles instead of 192 (exchange half
//          your live values per step; final lane->t map = 5-bit reversal).
// Phase 2: chunk softmax partials + ballot-compaction of nonzero (p,t).
// Phase 3: branch-free compacted context accumulation (round-2 win, kept).
// ---------------------------------------------------------------------------
__global__ __launch_bounds__(256) void fused_kernel(
    const float* __restrict__ pm, const float* __restrict__ awcat,
    const float* __restrict__ pq, const float* __restrict__ M,
    const float* __restrict__ Wv, const int* __restrict__ mask,
    const float* __restrict__ memory,
    float* __restrict__ pbuf, float* __restrict__ pmax,
    float* __restrict__ psum, float* __restrict__ pctx)
{
    const int b   = blockIdx.y;
    const int cx  = blockIdx.x;
    const int t0  = cx * CT;             // block covers [t0, t0+64)
    const int tid = threadIdx.x;
    const int s   = tid >> 7;            // tile 0/1
    const int a   = tid & 127;
    const int ts  = t0 + TT * s;

    __shared__ float saw0[96], saw1[96];     // aw[c, t0-15 .. t0+78]
    __shared__ float sred[2][2][TT];         // [tile][a-half][t]
    __shared__ float2 swt[CT];               // compacted (p, t-as-bits)
    __shared__ int   scount;                 // number of compacted rows
    __shared__ float4 sacc[128];

    for (int i = tid; i < 94; i += 256){
        int tt = t0 - PADL + i;
        bool ok = (tt >= 0) && (tt < T_);
        saw0[i] = ok ? awcat[(b*2+0)*T_ + tt] : 0.f;
        saw1[i] = ok ? awcat[(b*2+1)*T_ + tt] : 0.f;
    }
    __syncthreads();

    // ---- Phase 1: acc init = pq + pm (loads issued up front) ----
    const float pqa = pq[b*DATT + a];
    const float wv  = Wv[a];
    const float* pmb = pm + ((size_t)(b*T_ + ts)) * DATT + a;

    float acc[TT];
    #pragma unroll
    for (int t = 0; t < TT; ++t) acc[t] = pqa + pmb[(size_t)t * DATT];

    // merged conv matrix rows (register FIR taps)
    float Ma0[KS], Ma1[KS];
    const float* Mrow = M + a*MP;
    #pragma unroll
    for (int k = 0; k < KS; ++k){ Ma0[k] = Mrow[k]; Ma1[k] = Mrow[KS + k]; }

    #pragma unroll
    for (int j = 0; j < TT + KS - 1; ++j){
        const float av0 = saw0[j + TT*s];
        const float av1 = saw1[j + TT*s];
        const int tlo = (j - KS + 1) > 0 ? (j - KS + 1) : 0;
        const int thi = (j < TT - 1) ? j : (TT - 1);
        #pragma unroll
        for (int t = tlo; t <= thi; ++t){
            acc[t] = fmaf(Ma0[j - t], av0, acc[t]);
            acc[t] = fmaf(Ma1[j - t], av1, acc[t]);
        }
    }

    #pragma unroll
    for (int t = 0; t < TT; ++t){
        acc[t] = wv * fast_tanh(acc[t]);
    }

    // ---- multi-value butterfly reduce over the wave's 64 lanes ----
    const int lane = tid & 63;
    const int half = a >> 6;
    #pragma unroll
    for (int k = 0; k < 16; ++k){
        const bool hi = (lane & 1) != 0;
        float send = hi ? acc[k] : acc[k+16];
        float recv = __shfl_xor(send, 1, 64);
        acc[k] = (hi ? acc[k+16] : acc[k]) + recv;
    }
    #pragma unroll
    for (int k = 0; k < 8; ++k){
        const bool hi = (lane & 2) != 0;
        float send = hi ? acc[k] : acc[k+8];
        float recv = __shfl_xor(send, 2, 64);
        acc[k] = (hi ? acc[k+8] : acc[k]) + recv;
    }
    #pragma unroll
    for (int k = 0; k < 4; ++k){
        const bool hi = (lane & 4) != 0;
        float send = hi ? acc[k] : acc[k+4];
        float recv = __shfl_xor(send, 4, 64);
        acc[k] = (hi ? acc[k+4] : acc[k]) + recv;
    }
    #pragma unroll
    for (int k = 0; k < 2; ++k){
        const bool hi = (lane & 8) != 0;
        float send = hi ? acc[k] : acc[k+2];
        float recv = __shfl_xor(send, 8, 64);
        acc[k] = (hi ? acc[k+2] : acc[k]) + recv;
    }
    {
        const bool hi = (lane & 16) != 0;
        float send = hi ? acc[0] : acc[1];
        float recv = __shfl_xor(send, 16, 64);
        acc[0] = (hi ? acc[1] : acc[0]) + recv;
    }
    acc[0] += __shfl_xor(acc[0], 32, 64);
    // lane -> t: 5-bit reversal of lane&31
    const int trev = ((lane & 1) << 4) | (((lane >> 1) & 1) << 3) |
                     (((lane >> 2) & 1) << 2) | (((lane >> 3) & 1) << 1) |
                     ((lane >> 4) & 1);
    if (lane < 32) sred[s][half][trev] = acc[0];
    __syncthreads();

    // ---- Phase 2: chunk softmax partials + ballot-compaction (1 wave) ----
    if (tid < 64){
        const int t = t0 + tid;
        float e = sred[tid>>5][0][tid&31] + sred[tid>>5][1][tid&31];
        const int mk = mask[b*T_ + t];
        float mval = mk ? -1e30f : e;
        #pragma unroll
        for (int off = 1; off < 64; off <<= 1) mval = fmaxf(mval, __shfl_xor(mval, off, 64));
        const float pval = mk ? 0.f : __expf(e - mval);
        float sv = pval;
        #pragma unroll
        for (int off = 1; off < 64; off <<= 1) sv += __shfl_xor(sv, off, 64);
        pbuf[b*T_ + t] = pval;
        const unsigned long long bal = __ballot(pval != 0.f);
        if (pval != 0.f){
            const int pfx = (int)__popcll(bal & ((1ull << tid) - 1ull));
            swt[pfx] = make_float2(pval, __int_as_float(tid));
        }
        if (tid == 0){
            scount = (int)__popcll(bal);
            pmax[b*NC + cx] = mval;
            psum[b*NC + cx] = sv;
        }
    }
    __syncthreads();

    // ---- Phase 3: partial context over compacted rows, branch-free ----
    const int n   = scount;
    const int col = tid & 127;   // float4 column (DEMB/4 = 128)
    const int row = tid >> 7;    // 2 entries in flight
    float4 a4 = make_float4(0.f, 0.f, 0.f, 0.f);
    const float4* mem4 = (const float4*)memory + ((size_t)(b*T_ + t0))*(DEMB/4) + col;

    int i = row;
    for (; i + 6 < n; i += 8){
        const float2 e0 = swt[i];
        const float2 e1 = swt[i+2];
        const float2 e2 = swt[i+4];
        const float2 e3 = swt[i+6];
        const float4 m0 = mem4[(size_t)__float_as_int(e0.y) * (DEMB/4)];
        const float4 m1 = mem4[(size_t)__float_as_int(e1.y) * (DEMB/4)];
        const float4 m2 = mem4[(size_t)__float_as_int(e2.y) * (DEMB/4)];
        const float4 m3 = mem4[(size_t)__float_as_int(e3.y) * (DEMB/4)];
        a4.x = fmaf(e0.x, m0.x, a4.x); a4.y = fmaf(e0.x, m0.y, a4.y);
        a4.z = fmaf(e0.x, m0.z, a4.z); a4.w = fmaf(e0.x, m0.w, a4.w);
        a4.x = fmaf(e1.x, m1.x, a4.x); a4.y = fmaf(e1.x, m1.y, a4.y);
        a4.z = fmaf(e1.x, m1.z, a4.z); a4.w = fmaf(e1.x, m1.w, a4.w);
        a4.x = fmaf(e2.x, m2.x, a4.x); a4.y = fmaf(e2.x, m2.y, a4.y);
        a4.z = fmaf(e2.x, m2.z, a4.z); a4.w = fmaf(e2.x, m2.w, a4.w);
        a4.x = fmaf(e3.x, m3.x, a4.x); a4.y = fmaf(e3.x, m3.y, a4.y);
        a4.z = fmaf(e3.x, m3.z, a4.z); a4.w = fmaf(e3.x, m3.w, a4.w);
    }
    for (; i < n; i += 2){
        const float2 e = swt[i];
        const float4 m = mem4[(size_t)__float_as_int(e.y) * (DEMB/4)];
        a4.x = fmaf(e.x, m.x, a4.x); a4.y = fmaf(e.x, m.y, a4.y);
        a4.z = fmaf(e.x, m.z, a4.z); a4.w = fmaf(e.x, m.w, a4.w);
    }

    if (row == 1) sacc[col] = a4;
    __syncthreads();
    if (row == 0){
        const float4 o = sacc[col];
        float4* dst = (float4*)(pctx + ((size_t)(b*NC + cx))*DEMB) + col;
        *dst = make_float4(a4.x + o.x, a4.y + o.y, a4.z + o.z, a4.w + o.w);
    }
}

// ---------------------------------------------------------------------------
// K3 (finalize): per b — global max/Z from chunk partials, then
//   ctx[d]  = sum_c scale_c * pctx_c[d],  scale_c = exp(m_c - g)/Z
//   w[t]    = p[t] * scale_{c(t)}
// ---------------------------------------------------------------------------
__global__ __launch_bounds__(256) void finalize_kernel(
    const float* __restrict__ pbuf, const float* __restrict__ pmax,
    const float* __restrict__ psum, const float* __restrict__ pctx,
    float* __restrict__ ctx, float* __restrict__ wout)
{
    const int b = blockIdx.x;
    const int tid = threadIdx.x;
    __shared__ float sscale[NC];

    if (tid < 64){
        float mv = (tid < NC) ? pmax[b*NC + tid] : -1e30f;
        float sv = (tid < NC) ? psum[b*NC + tid] : 0.f;
        float g = mv;
        #pragma unroll
        for (int off = 1; off < 64; off <<= 1) g = fmaxf(g, __shfl_xor(g, off, 64));
        float z = sv * __expf(mv - g);
        #pragma unroll
        for (int off = 1; off < 64; off <<= 1) z += __shfl_xor(z, off, 64);
        if (tid < NC) sscale[tid] = __expf(mv - g) / z;
    }
    __syncthreads();

    // ctx: 256 threads x float2 = 512 d's
    float2 a2 = make_float2(0.f, 0.f);
    const float2* pc2 = (const float2*)(pctx + (size_t)b*NC*DEMB) + tid;
    #pragma unroll
    for (int c = 0; c < NC; ++c){
        const float sc = sscale[c];
        if (sc != 0.f){
            const float2 v = pc2[(size_t)c * (DEMB/2)];
            a2.x = fmaf(sc, v.x, a2.x);
            a2.y = fmaf(sc, v.y, a2.y);
        }
    }
    ((float2*)(ctx + b*DEMB))[tid] = a2;

    // weights
    #pragma unroll
    for (int i = 0; i < T_/256; ++i){
        const int t = tid + 256*i;
        wout[b*T_ + t] = pbuf[b*T_ + t] * sscale[t >> 6];
    }
}

// ---------------------------------------------------------------------------
extern "C" void kernel_launch(void* const* d_in, const int* in_sizes, int n_in,
                              void* d_out, int out_size, void* d_ws, size_t ws_size,
                              hipStream_t stream)
{
    const float* hidden = (const float*)d_in[0];   // (B, D_RNN)
    const float* memory = (const float*)d_in[1];   // (B, T, D_EMB)
    const float* pm     = (const float*)d_in[2];   // (B, T, D_ATT)
    const float* awcat  = (const float*)d_in[3];   // (B, 2, T)
    const int*   mask   = (const int*)d_in[4];     // (B, T)
    const float* Wq     = (const float*)d_in[5];   // (D_ATT, D_RNN)
    const float* Wv     = (const float*)d_in[6];   // (1, D_ATT)
    const float* convw  = (const float*)d_in[7];   // (NF, 2, KS)
    const float* Wd     = (const float*)d_in[8];   // (D_ATT, NF)

    float* out  = (float*)d_out;
    float* ctx  = out;               // (B, D_EMB)
    float* wout = out + B_*DEMB;     // (B, T)

    float* pq    = (float*)d_ws;             // 8192
    float* M     = pq   + B_*DATT;           // 8192
    float* pbuf  = M    + DATT*MP;           // B*T = 131072
    float* pmax  = pbuf + B_*T_;             // B*NC = 2048
    float* psum  = pmax + B_*NC;             // 2048
    float* pctx  = psum + B_*NC;             // B*NC*DEMB = 4 MB

    prep_kernel<<<dim3(B_ + 1), 128, 0, stream>>>(hidden, Wq, Wd, convw, pq, M);
    fused_kernel<<<dim3(NC, B_), 256, 0, stream>>>(pm, awcat, pq, M, Wv, mask,
                                                   memory, pbuf, pmax, psum, pctx);
    finalize_kernel<<<dim3(B_), 256, 0, stream>>>(pbuf, pmax, psum, pctx, ctx, wout);
}

// Round 4
// 439.196 us; speedup vs baseline: 1.2328x; 1.0046x over previous
//
#include <hip/hip_runtime.h>
#include <math.h>

#define B_    64
#define T_    2048
#define DRNN  1024
#define DEMB  512
#define DATT  128
#define NF    32
#define KS    31
#define PADL  15
#define TT    32   // t's per thread-tile in energy phase
#define CT    64   // t's per block (chunk)
#define NC    (T_/CT)   // 32 chunks per batch row

__device__ __forceinline__ float fast_tanh(float x){
    float e2 = __expf(2.0f * x);
    return 1.0f - 2.0f / (e2 + 1.0f);
}

// ---------------------------------------------------------------------------
// K1: pq[b,a] = hidden[b,:] . Wq[a,:]   (blocks 0..63; one WAVE per 32 a's,
//     lanes split K -> Wq reads fully coalesced, shuffle-tree reduce; the old
//     version had lane-stride-4KB loads feeding a serial 1024-FMA chain)
//     M2[ck*DATT + a] = sum_f Wd[a,f]*conv_w[f,ck]   (block 64, TRANSPOSED
//     so fused's 62 tap loads are coalesced across lanes)
// ---------------------------------------------------------------------------
__global__ __launch_bounds__(256) void prep_kernel(
    const float* __restrict__ hidden, const float* __restrict__ Wq,
    const float* __restrict__ Wd, const float* __restrict__ convw,
    float* __restrict__ pq, float* __restrict__ M2)
{
    const int blk = blockIdx.x;
    const int tid = threadIdx.x;
    if (blk < B_) {
        const int b    = blk;
        const int lane = tid & 63;
        const int w    = tid >> 6;           // wave 0..3 -> a in [w*32, w*32+32)
        // each lane holds its 16 k's of hidden[b] (coalesced float4 loads)
        float4 h[4];
        #pragma unroll
        for (int j = 0; j < 4; ++j)
            h[j] = *(const float4*)(hidden + b*DRNN + lane*4 + j*256);
        for (int ai = 0; ai < 32; ++ai){
            const int a = w*32 + ai;
            const float4* wq4 = (const float4*)(Wq + (size_t)a*DRNN);
            float acc = 0.f;
            #pragma unroll
            for (int j = 0; j < 4; ++j){
                const float4 q = wq4[lane + j*64];   // coalesced
                acc = fmaf(q.x, h[j].x, acc);
                acc = fmaf(q.y, h[j].y, acc);
                acc = fmaf(q.z, h[j].z, acc);
                acc = fmaf(q.w, h[j].w, acc);
            }
            acc += __shfl_xor(acc, 1, 64);  acc += __shfl_xor(acc, 2, 64);
            acc += __shfl_xor(acc, 4, 64);  acc += __shfl_xor(acc, 8, 64);
            acc += __shfl_xor(acc, 16, 64); acc += __shfl_xor(acc, 32, 64);
            if (lane == 0) pq[b*DATT + a] = acc;
        }
    } else {
        const int a = tid & 127;
        const int h = tid >> 7;              // each half does 31 of the 62 cols
        float wd[NF];
        #pragma unroll
        for (int f = 0; f < NF; ++f) wd[f] = Wd[a*NF + f];
        for (int ck = h*KS; ck < h*KS + KS; ++ck){
            float acc = 0.f;
            #pragma unroll
            for (int f = 0; f < NF; ++f) acc = fmaf(wd[f], convw[f*2*KS + ck], acc);
            M2[ck*DATT + a] = acc;           // transposed store (coalesced)
        }
    }
}

// ---------------------------------------------------------------------------
// K2 (fused energy + chunk-softmax + partial context).
// Grid: x = NC, y = B. Block = 256.
// Staging: aw halo + 64-bit mask bitmap (one ballot, lives in 2 LDS words).
// Phase 1: pm loads issued FIRST, directly into acc[t] (zero extra VGPRs),
//          SKIPPED for masked t via wave-uniform SGPR bit tests (saves
//          ~32 MB HBM); Ma taps from transposed M2 (coalesced); register
//          FIR; tanh; multi-value butterfly reduce (32 shuffles).
// Phase 2: chunk softmax partials + ballot-compaction of nonzero (p,t).
// Phase 3: branch-free compacted context, 8 loads in flight per thread.
// ---------------------------------------------------------------------------
__global__ __launch_bounds__(256) void fused_kernel(
    const float* __restrict__ pm, const float* __restrict__ awcat,
    const float* __restrict__ pq, const float* __restrict__ M2,
    const float* __restrict__ Wv, const int* __restrict__ mask,
    const float* __restrict__ memory,
    float* __restrict__ pbuf, float* __restrict__ pmax,
    float* __restrict__ psum, float* __restrict__ pctx)
{
    const int b   = blockIdx.y;
    const int cx  = blockIdx.x;
    const int t0  = cx * CT;             // block covers [t0, t0+64)
    const int tid = threadIdx.x;
    const int s   = tid >> 7;            // tile 0/1
    const int a   = tid & 127;
    const int ts  = t0 + TT * s;

    __shared__ float saw0[96], saw1[96];     // aw[c, t0-15 .. t0+78]
    __shared__ float sred[2][2][TT];         // [tile][a-half][t]
    __shared__ float2 swt[CT];               // compacted (p, t-as-bits)
    __shared__ int   scount;                 // number of compacted rows
    __shared__ float4 sacc[128];
    __shared__ unsigned int smkbits[2];      // mask bitmap for [t0, t0+64)

    for (int i = tid; i < 94; i += 256){
        int tt = t0 - PADL + i;
        bool ok = (tt >= 0) && (tt < T_);
        saw0[i] = ok ? awcat[(b*2+0)*T_ + tt] : 0.f;
        saw1[i] = ok ? awcat[(b*2+1)*T_ + tt] : 0.f;
    }
    if (tid < 64){                            // wave 0 exactly
        const int mk = mask[b*T_ + t0 + tid] != 0;
        const unsigned long long bal = __ballot(mk);
        if (tid == 0){
            smkbits[0] = (unsigned)bal;
            smkbits[1] = (unsigned)(bal >> 32);
        }
    }
    __syncthreads();

    // ---- Phase 1 ----
    const float pqa = pq[b*DATT + a];
    const float wv  = Wv[a];
    const unsigned mkb = __builtin_amdgcn_readfirstlane(smkbits[s]); // SGPR

    // pm loads straight into acc (issued up front, no consumers yet);
    // masked t: skip the load entirely (wave-uniform scalar branch)
    const float* pmb = pm + ((size_t)(b*T_ + ts)) * DATT + a;
    float acc[TT];
    #pragma unroll
    for (int t = 0; t < TT; ++t){
        acc[t] = 0.f;
        if (((mkb >> t) & 1u) == 0u) acc[t] = pmb[(size_t)t * DATT];
    }

    // merged conv taps from transposed M2 (coalesced across lanes)
    float Ma0[KS], Ma1[KS];
    const float* M2a = M2 + a;
    #pragma unroll
    for (int k = 0; k < KS; ++k){
        Ma0[k] = M2a[(size_t)k * DATT];
        Ma1[k] = M2a[(size_t)(KS + k) * DATT];
    }

    #pragma unroll
    for (int t = 0; t < TT; ++t) acc[t] += pqa;   // adds after all loads issued

    #pragma unroll
    for (int j = 0; j < TT + KS - 1; ++j){
        const float av0 = saw0[j + TT*s];
        const float av1 = saw1[j + TT*s];
        const int tlo = (j - KS + 1) > 0 ? (j - KS + 1) : 0;
        const int thi = (j < TT - 1) ? j : (TT - 1);
        #pragma unroll
        for (int t = tlo; t <= thi; ++t){
            acc[t] = fmaf(Ma0[j - t], av0, acc[t]);
            acc[t] = fmaf(Ma1[j - t], av1, acc[t]);
        }
    }

    #pragma unroll
    for (int t = 0; t < TT; ++t){
        acc[t] = wv * fast_tanh(acc[t]);
    }

    // ---- multi-value butterfly reduce over the wave's 64 lanes ----
    const int lane = tid & 63;
    const int half = a >> 6;
    #pragma unroll
    for (int k = 0; k < 16; ++k){
        const bool hi = (lane & 1) != 0;
        float send = hi ? acc[k] : acc[k+16];
        float recv = __shfl_xor(send, 1, 64);
        acc[k] = (hi ? acc[k+16] : acc[k]) + recv;
    }
    #pragma unroll
    for (int k = 0; k < 8; ++k){
        const bool hi = (lane & 2) != 0;
        float send = hi ? acc[k] : acc[k+8];
        float recv = __shfl_xor(send, 2, 64);
        acc[k] = (hi ? acc[k+8] : acc[k]) + recv;
    }
    #pragma unroll
    for (int k = 0; k < 4; ++k){
        const bool hi = (lane & 4) != 0;
        float send = hi ? acc[k] : acc[k+4];
        float recv = __shfl_xor(send, 4, 64);
        acc[k] = (hi ? acc[k+4] : acc[k]) + recv;
    }
    #pragma unroll
    for (int k = 0; k < 2; ++k){
        const bool hi = (lane & 8) != 0;
        float send = hi ? acc[k] : acc[k+2];
        float recv = __shfl_xor(send, 8, 64);
        acc[k] = (hi ? acc[k+2] : acc[k]) + recv;
    }
    {
        const bool hi = (lane & 16) != 0;
        float send = hi ? acc[0] : acc[1];
        float recv = __shfl_xor(send, 16, 64);
        acc[0] = (hi ? acc[1] : acc[0]) + recv;
    }
    acc[0] += __shfl_xor(acc[0], 32, 64);
    // lane -> t: 5-bit reversal of lane&31
    const int trev = ((lane & 1) << 4) | (((lane >> 1) & 1) << 3) |
                     (((lane >> 2) & 1) << 2) | (((lane >> 3) & 1) << 1) |
                     ((lane >> 4) & 1);
    if (lane < 32) sred[s][half][trev] = acc[0];
    __syncthreads();

    // ---- Phase 2: chunk softmax partials + ballot-compaction (1 wave) ----
    if (tid < 64){
        const int t = t0 + tid;
        float e = sred[tid>>5][0][tid&31] + sred[tid>>5][1][tid&31];
        const int mk = (smkbits[tid>>5] >> (tid&31)) & 1u;
        float mval = mk ? -1e30f : e;
        #pragma unroll
        for (int off = 1; off < 64; off <<= 1) mval = fmaxf(mval, __shfl_xor(mval, off, 64));
        const float pval = mk ? 0.f : __expf(e - mval);
        float sv = pval;
        #pragma unroll
        for (int off = 1; off < 64; off <<= 1) sv += __shfl_xor(sv, off, 64);
        pbuf[b*T_ + t] = pval;
        const unsigned long long bal = __ballot(pval != 0.f);
        if (pval != 0.f){
            const int pfx = (int)__popcll(bal & ((1ull << tid) - 1ull));
            swt[pfx] = make_float2(pval, __int_as_float(tid));
        }
        if (tid == 0){
            scount = (int)__popcll(bal);
            pmax[b*NC + cx] = mval;
            psum[b*NC + cx] = sv;
        }
    }
    __syncthreads();

    // ---- Phase 3: partial context over compacted rows, branch-free ----
    const int n   = scount;
    const int col = tid & 127;   // float4 column (DEMB/4 = 128)
    const int row = tid >> 7;    // 2 entries in flight
    float4 a4 = make_float4(0.f, 0.f, 0.f, 0.f);
    const float4* mem4 = (const float4*)memory + ((size_t)(b*T_ + t0))*(DEMB/4) + col;

    int i = row;
    for (; i + 14 < n; i += 16){             // 8 loads in flight
        float2 e[8];
        #pragma unroll
        for (int u = 0; u < 8; ++u) e[u] = swt[i + 2*u];
        float4 m[8];
        #pragma unroll
        for (int u = 0; u < 8; ++u)
            m[u] = mem4[(size_t)__float_as_int(e[u].y) * (DEMB/4)];
        #pragma unroll
        for (int u = 0; u < 8; ++u){
            a4.x = fmaf(e[u].x, m[u].x, a4.x);
            a4.y = fmaf(e[u].x, m[u].y, a4.y);
            a4.z = fmaf(e[u].x, m[u].z, a4.z);
            a4.w = fmaf(e[u].x, m[u].w, a4.w);
        }
    }
    for (; i + 6 < n; i += 8){               // 4 loads in flight
        const float2 e0 = swt[i];
        const float2 e1 = swt[i+2];
        const float2 e2 = swt[i+4];
        const float2 e3 = swt[i+6];
        const float4 m0 = mem4[(size_t)__float_as_int(e0.y) * (DEMB/4)];
        const float4 m1 = mem4[(size_t)__float_as_int(e1.y) * (DEMB/4)];
        const float4 m2 = mem4[(size_t)__float_as_int(e2.y) * (DEMB/4)];
        const float4 m3 = mem4[(size_t)__float_as_int(e3.y) * (DEMB/4)];
        a4.x = fmaf(e0.x, m0.x, a4.x); a4.y = fmaf(e0.x, m0.y, a4.y);
        a4.z = fmaf(e0.x, m0.z, a4.z); a4.w = fmaf(e0.x, m0.w, a4.w);
        a4.x = fmaf(e1.x, m1.x, a4.x); a4.y = fmaf(e1.x, m1.y, a4.y);
        a4.z = fmaf(e1.x, m1.z, a4.z); a4.w = fmaf(e1.x, m1.w, a4.w);
        a4.x = fmaf(e2.x, m2.x, a4.x); a4.y = fmaf(e2.x, m2.y, a4.y);
        a4.z = fmaf(e2.x, m2.z, a4.z); a4.w = fmaf(e2.x, m2.w, a4.w);
        a4.x = fmaf(e3.x, m3.x, a4.x); a4.y = fmaf(e3.x, m3.y, a4.y);
        a4.z = fmaf(e3.x, m3.z, a4.z); a4.w = fmaf(e3.x, m3.w, a4.w);
    }
    for (; i < n; i += 2){
        const float2 e = swt[i];
        const float4 m = mem4[(size_t)__float_as_int(e.y) * (DEMB/4)];
        a4.x = fmaf(e.x, m.x, a4.x); a4.y = fmaf(e.x, m.y, a4.y);
        a4.z = fmaf(e.x, m.z, a4.z); a4.w = fmaf(e.x, m.w, a4.w);
    }

    if (row == 1) sacc[col] = a4;
    __syncthreads();
    if (row == 0){
        const float4 o = sacc[col];
        float4* dst = (float4*)(pctx + ((size_t)(b*NC + cx))*DEMB) + col;
        *dst = make_float4(a4.x + o.x, a4.y + o.y, a4.z + o.z, a4.w + o.w);
    }
}

// ---------------------------------------------------------------------------
// K3 (finalize): per b — global max/Z from chunk partials, then
//   ctx[d]  = sum_c scale_c * pctx_c[d],  scale_c = exp(m_c - g)/Z
//   w[t]    = p[t] * scale_{c(t)}
// ---------------------------------------------------------------------------
__global__ __launch_bounds__(256) void finalize_kernel(
    const float* __restrict__ pbuf, const float* __restrict__ pmax,
    const float* __restrict__ psum, const float* __restrict__ pctx,
    float* __restrict__ ctx, float* __restrict__ wout)
{
    const int b = blockIdx.x;
    const int tid = threadIdx.x;
    __shared__ float sscale[NC];

    if (tid < 64){
        float mv = (tid < NC) ? pmax[b*NC + tid] : -1e30f;
        float sv = (tid < NC) ? psum[b*NC + tid] : 0.f;
        float g = mv;
        #pragma unroll
        for (int off = 1; off < 64; off <<= 1) g = fmaxf(g, __shfl_xor(g, off, 64));
        float z = sv * __expf(mv - g);
        #pragma unroll
        for (int off = 1; off < 64; off <<= 1) z += __shfl_xor(z, off, 64);
        if (tid < NC) sscale[tid] = __expf(mv - g) / z;
    }
    __syncthreads();

    // ctx: 256 threads x float2 = 512 d's
    float2 a2 = make_float2(0.f, 0.f);
    const float2* pc2 = (const float2*)(pctx + (size_t)b*NC*DEMB) + tid;
    #pragma unroll
    for (int c = 0; c < NC; ++c){
        const float sc = sscale[c];
        if (sc != 0.f){
            const float2 v = pc2[(size_t)c * (DEMB/2)];
            a2.x = fmaf(sc, v.x, a2.x);
            a2.y = fmaf(sc, v.y, a2.y);
        }
    }
    ((float2*)(ctx + b*DEMB))[tid] = a2;

    // weights
    #pragma unroll
    for (int i = 0; i < T_/256; ++i){
        const int t = tid + 256*i;
        wout[b*T_ + t] = pbuf[b*T_ + t] * sscale[t >> 6];
    }
}

// ---------------------------------------------------------------------------
extern "C" void kernel_launch(void* const* d_in, const int* in_sizes, int n_in,
                              void* d_out, int out_size, void* d_ws, size_t ws_size,
                              hipStream_t stream)
{
    const float* hidden = (const float*)d_in[0];   // (B, D_RNN)
    const float* memory = (const float*)d_in[1];   // (B, T, D_EMB)
    const float* pm     = (const float*)d_in[2];   // (B, T, D_ATT)
    const float* awcat  = (const float*)d_in[3];   // (B, 2, T)
    const int*   mask   = (const int*)d_in[4];     // (B, T)
    const float* Wq     = (const float*)d_in[5];   // (D_ATT, D_RNN)
    const float* Wv     = (const float*)d_in[6];   // (1, D_ATT)
    const float* convw  = (const float*)d_in[7];   // (NF, 2, KS)
    const float* Wd     = (const float*)d_in[8];   // (D_ATT, NF)

    float* out  = (float*)d_out;
    float* ctx  = out;               // (B, D_EMB)
    float* wout = out + B_*DEMB;     // (B, T)

    float* pq    = (float*)d_ws;             // 8192
    float* M2    = pq   + B_*DATT;           // 8192 (62*128 used)
    float* pbuf  = M2   + 8192;              // B*T = 131072
    float* pmax  = pbuf + B_*T_;             // B*NC = 2048
    float* psum  = pmax + B_*NC;             // 2048
    float* pctx  = psum + B_*NC;             // B*NC*DEMB = 4 MB

    prep_kernel<<<dim3(B_ + 1), 256, 0, stream>>>(hidden, Wq, Wd, convw, pq, M2);
    fused_kernel<<<dim3(NC, B_), 256, 0, stream>>>(pm, awcat, pq, M2, Wv, mask,
                                                   memory, pbuf, pmax, psum, pctx);
    finalize_kernel<<<dim3(B_), 256, 0, stream>>>(pbuf, pmax, psum, pctx, ctx, wout);
}

// Round 5
// 404.966 us; speedup vs baseline: 1.3371x; 1.0845x over previous
//
#include <hip/hip_runtime.h>
#include <math.h>

#define B_    64
#define T_    2048
#define DRNN  1024
#define DEMB  512
#define DATT  128
#define NF    32
#define KS    31
#define PADL  15
#define TT    32   // t's per thread-tile in energy phase
#define CT    64   // t's per block (chunk)
#define NC    (T_/CT)   // 32 chunks per batch row

__device__ __forceinline__ float fast_tanh(float x){
    float e2 = __expf(2.0f * x);
    return 1.0f - 2.0f / (e2 + 1.0f);
}

// ---------------------------------------------------------------------------
// K1: pq[b,a] = hidden[b,:] . Wq[a,:]   (blocks 0..63; 512 thr = 8 waves,
//     each wave 16 a's, lanes split K -> coalesced Wq + shuffle reduce)
//     M2[ck*DATT + a] = sum_f Wd[a,f]*conv_w[f,ck]   (block 64, transposed)
// ---------------------------------------------------------------------------
__global__ __launch_bounds__(512) void prep_kernel(
    const float* __restrict__ hidden, const float* __restrict__ Wq,
    const float* __restrict__ Wd, const float* __restrict__ convw,
    float* __restrict__ pq, float* __restrict__ M2)
{
    const int blk = blockIdx.x;
    const int tid = threadIdx.x;
    if (blk < B_) {
        const int b    = blk;
        const int lane = tid & 63;
        const int w    = tid >> 6;           // wave 0..7 -> a in [w*16, w*16+16)
        float4 h[4];
        #pragma unroll
        for (int j = 0; j < 4; ++j)
            h[j] = *(const float4*)(hidden + b*DRNN + lane*4 + j*256);
        for (int ai = 0; ai < 16; ++ai){
            const int a = w*16 + ai;
            const float4* wq4 = (const float4*)(Wq + (size_t)a*DRNN);
            float acc = 0.f;
            #pragma unroll
            for (int j = 0; j < 4; ++j){
                const float4 q = wq4[lane + j*64];   // coalesced
                acc = fmaf(q.x, h[j].x, acc);
                acc = fmaf(q.y, h[j].y, acc);
                acc = fmaf(q.z, h[j].z, acc);
                acc = fmaf(q.w, h[j].w, acc);
            }
            acc += __shfl_xor(acc, 1, 64);  acc += __shfl_xor(acc, 2, 64);
            acc += __shfl_xor(acc, 4, 64);  acc += __shfl_xor(acc, 8, 64);
            acc += __shfl_xor(acc, 16, 64); acc += __shfl_xor(acc, 32, 64);
            if (lane == 0) pq[b*DATT + a] = acc;
        }
    } else {
        const int a = tid & 127;
        const int g = tid >> 7;              // 0..3, each ~16 of 62 cols
        float wd[NF];
        #pragma unroll
        for (int f = 0; f < NF; ++f) wd[f] = Wd[a*NF + f];
        const int cklo = g*16;
        const int ckhi = (g*16 + 16 < 2*KS) ? (g*16 + 16) : 2*KS;
        for (int ck = cklo; ck < ckhi; ++ck){
            float acc = 0.f;
            #pragma unroll
            for (int f = 0; f < NF; ++f) acc = fmaf(wd[f], convw[f*2*KS + ck], acc);
            M2[ck*DATT + a] = acc;           // transposed store (coalesced)
        }
    }
}

// ---------------------------------------------------------------------------
// K2 (fused energy + chunk-softmax + partial context).
// Grid: x = NC, y = B. Block = 256. __launch_bounds__(256,4): force <=128
// VGPR -> 4 waves/SIMD (the FIR live set acc[32]+taps[62] ~94 fits; the old
// kernel's 8-deep phase-3 unroll pushed past 128 -> 2 waves/SIMD, which is
// the theory for why all round-4 micro-fixes were neutral).
// Phase 1: per-wave mask ballot (SGPR, no LDS/barrier), then pm->acc and tap
//          loads issued BEFORE the staging loop (fly under staging+barrier);
//          register FIR; tanh; multi-value butterfly reduce.
// Phase 2: chunk softmax partials + ballot-compaction of nonzero (p,t).
// Phase 3: branch-free compacted context, 4-deep unroll (register-safe).
// ---------------------------------------------------------------------------
__global__ __launch_bounds__(256, 4) void fused_kernel(
    const float* __restrict__ pm, const float* __restrict__ awcat,
    const float* __restrict__ pq, const float* __restrict__ M2,
    const float* __restrict__ Wv, const int* __restrict__ mask,
    const float* __restrict__ memory,
    float* __restrict__ pbuf, float* __restrict__ pmax,
    float* __restrict__ psum, float* __restrict__ pctx)
{
    const int b   = blockIdx.y;
    const int cx  = blockIdx.x;
    const int t0  = cx * CT;             // block covers [t0, t0+64)
    const int tid = threadIdx.x;
    const int s   = tid >> 7;            // tile 0/1
    const int a   = tid & 127;
    const int ts  = t0 + TT * s;
    const int lane = tid & 63;

    __shared__ float saw0[96], saw1[96];     // aw[c, t0-15 .. t0+78]
    __shared__ float sred[2][2][TT];         // [tile][a-half][t]
    __shared__ float2 swt[CT];               // compacted (p, t-as-bits)
    __shared__ int   scount;                 // number of compacted rows
    __shared__ float4 sacc[128];
    __shared__ unsigned int smkbits[2];      // mask bitmap for phase 2

    // ---- per-wave mask ballot: bitmap for THIS wave's 32 t's, as SGPR ----
    int mymk = 0;
    if (lane < 32) mymk = (mask[b*T_ + ts + lane] != 0);
    const unsigned long long bal0 = __ballot(mymk);
    const unsigned mkb = (unsigned)bal0;     // wave-uniform scalar

    // ---- front-loaded globals: pm -> acc (masked t skipped), taps, pq, wv ----
    const float pqa = pq[b*DATT + a];
    const float wv  = Wv[a];
    const float* pmb = pm + ((size_t)(b*T_ + ts)) * DATT + a;
    float acc[TT];
    #pragma unroll
    for (int t = 0; t < TT; ++t){
        acc[t] = 0.f;
        if (((mkb >> t) & 1u) == 0u) acc[t] = pmb[(size_t)t * DATT];
    }
    float Ma0[KS], Ma1[KS];
    const float* M2a = M2 + a;
    #pragma unroll
    for (int k = 0; k < KS; ++k){
        Ma0[k] = M2a[(size_t)k * DATT];
        Ma1[k] = M2a[(size_t)(KS + k) * DATT];
    }

    // ---- staging: aw halo + phase-2 mask bitmap ----
    for (int i = tid; i < 94; i += 256){
        int tt = t0 - PADL + i;
        bool ok = (tt >= 0) && (tt < T_);
        saw0[i] = ok ? awcat[(b*2+0)*T_ + tt] : 0.f;
        saw1[i] = ok ? awcat[(b*2+1)*T_ + tt] : 0.f;
    }
    if (tid < 64){                            // wave 0 exactly
        const int mk = mask[b*T_ + t0 + tid] != 0;
        const unsigned long long bal = __ballot(mk);
        if (tid == 0){
            smkbits[0] = (unsigned)bal;
            smkbits[1] = (unsigned)(bal >> 32);
        }
    }
    __syncthreads();

    // ---- Phase 1: FIR ----
    #pragma unroll
    for (int t = 0; t < TT; ++t) acc[t] += pqa;

    #pragma unroll
    for (int j = 0; j < TT + KS - 1; ++j){
        const float av0 = saw0[j + TT*s];
        const float av1 = saw1[j + TT*s];
        const int tlo = (j - KS + 1) > 0 ? (j - KS + 1) : 0;
        const int thi = (j < TT - 1) ? j : (TT - 1);
        #pragma unroll
        for (int t = tlo; t <= thi; ++t){
            acc[t] = fmaf(Ma0[j - t], av0, acc[t]);
            acc[t] = fmaf(Ma1[j - t], av1, acc[t]);
        }
    }

    #pragma unroll
    for (int t = 0; t < TT; ++t){
        acc[t] = wv * fast_tanh(acc[t]);
    }

    // ---- multi-value butterfly reduce over the wave's 64 lanes ----
    const int half = a >> 6;
    #pragma unroll
    for (int k = 0; k < 16; ++k){
        const bool hi = (lane & 1) != 0;
        float send = hi ? acc[k] : acc[k+16];
        float recv = __shfl_xor(send, 1, 64);
        acc[k] = (hi ? acc[k+16] : acc[k]) + recv;
    }
    #pragma unroll
    for (int k = 0; k < 8; ++k){
        const bool hi = (lane & 2) != 0;
        float send = hi ? acc[k] : acc[k+8];
        float recv = __shfl_xor(send, 2, 64);
        acc[k] = (hi ? acc[k+8] : acc[k]) + recv;
    }
    #pragma unroll
    for (int k = 0; k < 4; ++k){
        const bool hi = (lane & 4) != 0;
        float send = hi ? acc[k] : acc[k+4];
        float recv = __shfl_xor(send, 4, 64);
        acc[k] = (hi ? acc[k+4] : acc[k]) + recv;
    }
    #pragma unroll
    for (int k = 0; k < 2; ++k){
        const bool hi = (lane & 8) != 0;
        float send = hi ? acc[k] : acc[k+2];
        float recv = __shfl_xor(send, 8, 64);
        acc[k] = (hi ? acc[k+2] : acc[k]) + recv;
    }
    {
        const bool hi = (lane & 16) != 0;
        float send = hi ? acc[0] : acc[1];
        float recv = __shfl_xor(send, 16, 64);
        acc[0] = (hi ? acc[1] : acc[0]) + recv;
    }
    acc[0] += __shfl_xor(acc[0], 32, 64);
    // lane -> t: 5-bit reversal of lane&31
    const int trev = ((lane & 1) << 4) | (((lane >> 1) & 1) << 3) |
                     (((lane >> 2) & 1) << 2) | (((lane >> 3) & 1) << 1) |
                     ((lane >> 4) & 1);
    if (lane < 32) sred[s][half][trev] = acc[0];
    __syncthreads();

    // ---- Phase 2: chunk softmax partials + ballot-compaction (1 wave) ----
    if (tid < 64){
        const int t = t0 + tid;
        float e = sred[tid>>5][0][tid&31] + sred[tid>>5][1][tid&31];
        const int mk = (smkbits[tid>>5] >> (tid&31)) & 1u;
        float mval = mk ? -1e30f : e;
        #pragma unroll
        for (int off = 1; off < 64; off <<= 1) mval = fmaxf(mval, __shfl_xor(mval, off, 64));
        const float pval = mk ? 0.f : __expf(e - mval);
        float sv = pval;
        #pragma unroll
        for (int off = 1; off < 64; off <<= 1) sv += __shfl_xor(sv, off, 64);
        pbuf[b*T_ + t] = pval;
        const unsigned long long bal = __ballot(pval != 0.f);
        if (pval != 0.f){
            const int pfx = (int)__popcll(bal & ((1ull << tid) - 1ull));
            swt[pfx] = make_float2(pval, __int_as_float(tid));
        }
        if (tid == 0){
            scount = (int)__popcll(bal);
            pmax[b*NC + cx] = mval;
            psum[b*NC + cx] = sv;
        }
    }
    __syncthreads();

    // ---- Phase 3: partial context over compacted rows, branch-free ----
    const int n   = scount;
    const int col = tid & 127;   // float4 column (DEMB/4 = 128)
    const int row = tid >> 7;    // 2 entries in flight
    float4 a4 = make_float4(0.f, 0.f, 0.f, 0.f);
    const float4* mem4 = (const float4*)memory + ((size_t)(b*T_ + t0))*(DEMB/4) + col;

    int i = row;
    for (; i + 6 < n; i += 8){               // 4 loads in flight
        const float2 e0 = swt[i];
        const float2 e1 = swt[i+2];
        const float2 e2 = swt[i+4];
        const float2 e3 = swt[i+6];
        const float4 m0 = mem4[(size_t)__float_as_int(e0.y) * (DEMB/4)];
        const float4 m1 = mem4[(size_t)__float_as_int(e1.y) * (DEMB/4)];
        const float4 m2 = mem4[(size_t)__float_as_int(e2.y) * (DEMB/4)];
        const float4 m3 = mem4[(size_t)__float_as_int(e3.y) * (DEMB/4)];
        a4.x = fmaf(e0.x, m0.x, a4.x); a4.y = fmaf(e0.x, m0.y, a4.y);
        a4.z = fmaf(e0.x, m0.z, a4.z); a4.w = fmaf(e0.x, m0.w, a4.w);
        a4.x = fmaf(e1.x, m1.x, a4.x); a4.y = fmaf(e1.x, m1.y, a4.y);
        a4.z = fmaf(e1.x, m1.z, a4.z); a4.w = fmaf(e1.x, m1.w, a4.w);
        a4.x = fmaf(e2.x, m2.x, a4.x); a4.y = fmaf(e2.x, m2.y, a4.y);
        a4.z = fmaf(e2.x, m2.z, a4.z); a4.w = fmaf(e2.x, m2.w, a4.w);
        a4.x = fmaf(e3.x, m3.x, a4.x); a4.y = fmaf(e3.x, m3.y, a4.y);
        a4.z = fmaf(e3.x, m3.z, a4.z); a4.w = fmaf(e3.x, m3.w, a4.w);
    }
    for (; i < n; i += 2){
        const float2 e = swt[i];
        const float4 m = mem4[(size_t)__float_as_int(e.y) * (DEMB/4)];
        a4.x = fmaf(e.x, m.x, a4.x); a4.y = fmaf(e.x, m.y, a4.y);
        a4.z = fmaf(e.x, m.z, a4.z); a4.w = fmaf(e.x, m.w, a4.w);
    }

    if (row == 1) sacc[col] = a4;
    __syncthreads();
    if (row == 0){
        const float4 o = sacc[col];
        float4* dst = (float4*)(pctx + ((size_t)(b*NC + cx))*DEMB) + col;
        *dst = make_float4(a4.x + o.x, a4.y + o.y, a4.z + o.z, a4.w + o.w);
    }
}

// ---------------------------------------------------------------------------
// K3 (finalize). Grid (8, B): every block recomputes the per-b scales (cheap,
// 64 floats from L2); block g==0 does ctx (BRANCH-FREE batched loads — the
// old per-chunk `if(sc!=0)` serialized 32 dependent loads on a 64-block grid);
// all blocks write their 256-t slice of wout.
// ---------------------------------------------------------------------------
__global__ __launch_bounds__(256) void finalize_kernel(
    const float* __restrict__ pbuf, const float* __restrict__ pmax,
    const float* __restrict__ psum, const float* __restrict__ pctx,
    float* __restrict__ ctx, float* __restrict__ wout)
{
    const int b   = blockIdx.y;
    const int g   = blockIdx.x;    // 0..7
    const int tid = threadIdx.x;
    __shared__ float sscale[NC];

    if (tid < 64){
        float mv = (tid < NC) ? pmax[b*NC + tid] : -1e30f;
        float sv = (tid < NC) ? psum[b*NC + tid] : 0.f;
        float gm = mv;
        #pragma unroll
        for (int off = 1; off < 64; off <<= 1) gm = fmaxf(gm, __shfl_xor(gm, off, 64));
        float z = sv * __expf(mv - gm);
        #pragma unroll
        for (int off = 1; off < 64; off <<= 1) z += __shfl_xor(z, off, 64);
        if (tid < NC) sscale[tid] = __expf(mv - gm) / z;
    }
    __syncthreads();

    if (g == 0){
        // ctx: 256 threads x float2 = 512 d's; loads batched (no branch)
        float2 a2 = make_float2(0.f, 0.f);
        const float2* pc2 = (const float2*)(pctx + (size_t)b*NC*DEMB) + tid;
        #pragma unroll
        for (int c = 0; c < NC; ++c){
            const float sc = sscale[c];
            const float2 v = pc2[(size_t)c * (DEMB/2)];
            a2.x = fmaf(sc, v.x, a2.x);
            a2.y = fmaf(sc, v.y, a2.y);
        }
        ((float2*)(ctx + b*DEMB))[tid] = a2;
    }

    // weights: this block's 256-t slice
    const int t = g*256 + tid;
    wout[b*T_ + t] = pbuf[b*T_ + t] * sscale[t >> 6];
}

// ---------------------------------------------------------------------------
extern "C" void kernel_launch(void* const* d_in, const int* in_sizes, int n_in,
                              void* d_out, int out_size, void* d_ws, size_t ws_size,
                              hipStream_t stream)
{
    const float* hidden = (const float*)d_in[0];   // (B, D_RNN)
    const float* memory = (const float*)d_in[1];   // (B, T, D_EMB)
    const float* pm     = (const float*)d_in[2];   // (B, T, D_ATT)
    const float* awcat  = (const float*)d_in[3];   // (B, 2, T)
    const int*   mask   = (const int*)d_in[4];     // (B, T)
    const float* Wq     = (const float*)d_in[5];   // (D_ATT, D_RNN)
    const float* Wv     = (const float*)d_in[6];   // (1, D_ATT)
    const float* convw  = (const float*)d_in[7];   // (NF, 2, KS)
    const float* Wd     = (const float*)d_in[8];   // (D_ATT, NF)

    float* out  = (float*)d_out;
    float* ctx  = out;               // (B, D_EMB)
    float* wout = out + B_*DEMB;     // (B, T)

    float* pq    = (float*)d_ws;             // 8192
    float* M2    = pq   + B_*DATT;           // 8192 (62*128 used)
    float* pbuf  = M2   + 8192;              // B*T = 131072
    float* pmax  = pbuf + B_*T_;             // B*NC = 2048
    float* psum  = pmax + B_*NC;             // 2048
    float* pctx  = psum + B_*NC;             // B*NC*DEMB = 4 MB

    prep_kernel<<<dim3(B_ + 1), 512, 0, stream>>>(hidden, Wq, Wd, convw, pq, M2);
    fused_kernel<<<dim3(NC, B_), 256, 0, stream>>>(pm, awcat, pq, M2, Wv, mask,
                                                   memory, pbuf, pmax, psum, pctx);
    finalize_kernel<<<dim3(8, B_), 256, 0, stream>>>(pbuf, pmax, psum, pctx, ctx, wout);
}